// Round 7
// baseline (211.660 us; speedup 1.0000x reference)
//
#include <hip/hip_runtime.h>

#define SEQ 8192
#define DM  128
#define NKS 8            // k-splits (1024 keys each)

typedef __attribute__((ext_vector_type(8)))  short bf16x8;
typedef __attribute__((ext_vector_type(16))) float f32x16;

static __device__ __forceinline__ unsigned short f2bf(float f) {
    unsigned int u = __builtin_bit_cast(unsigned int, f);
    u += 0x7FFFu + ((u >> 16) & 1u);
    return (unsigned short)(u >> 16);
}
static __device__ __forceinline__ unsigned int pack2bf(float a, float b) {
    return ((unsigned int)f2bf(b) << 16) | (unsigned int)f2bf(a);
}
static __device__ __forceinline__ float bflo(unsigned int u) {
    return __builtin_bit_cast(float, u << 16);
}
static __device__ __forceinline__ float bfhi(unsigned int u) {
    return __builtin_bit_cast(float, u & 0xFFFF0000u);
}
static __device__ __forceinline__ bf16x8 as_frag(uint4 v) {
    return __builtin_bit_cast(bf16x8, v);
}
static __device__ __forceinline__ unsigned int pack2bf_trunc(float a, float b) {
    return __builtin_amdgcn_perm(__builtin_bit_cast(unsigned int, b),
                                 __builtin_bit_cast(unsigned int, a), 0x07060302u);
}
static __device__ __forceinline__ void gl_lds16(const void* g, void* l) {
    __builtin_amdgcn_global_load_lds(
        (const __attribute__((address_space(1))) void*)(unsigned long long)g,
        (__attribute__((address_space(3))) void*)(unsigned int)(unsigned long long)l,
        16, 0, 0);
}
#define CL2 (1.4426950408889634f / 90.50966799187809f)   // log2(e)/sqrt(8192)

// ---- prep: 512 blocks; b<256: K-tile b, b>=256: V-tile (b-256) ------------
// Fragment-order tiles (chunk p = s*64 + h*32 + q, 16B chunks):
//   Kt: chunk(p) = K[tile*32+q][16s+8h .. +8)
//   Vt: chunk(p) = V^T[32*(p64>>1)+q][tile*32 + 16*(p64&1)+8h .. +8)
// Block 0 also zeroes the split-k counters (runs every launch).
__global__ __launch_bounds__(256) void prep_kernel(
        const float* __restrict__ K, const float* __restrict__ V,
        uint4* __restrict__ Kt, uint4* __restrict__ Vt, int* __restrict__ cnt) {
    __shared__ float TL[32 * 136];
    const int b = blockIdx.x, tid = threadIdx.x;
    const int which = b >> 8, tile = b & 255;
    if (b == 0 && tid < 64) cnt[tid] = 0;
    const float4* S4 = which ? (const float4*)V : (const float4*)K;
    #pragma unroll
    for (int u = 0; u < 4; ++u) {
        int f4 = u * 256 + tid;
        int k = f4 >> 5, c4 = f4 & 31;
        float4 v = S4[(size_t)tile * 1024 + f4];
        *(float4*)(TL + k * 136 + c4 * 4) = v;
    }
    __syncthreads();
    if (which == 0) {
        #pragma unroll
        for (int u = 0; u < 2; ++u) {
            int p = u * 256 + tid;
            int q = p & 31, h = (p >> 5) & 1, s = p >> 6;
            const float* src = TL + q * 136 + s * 16 + h * 8;
            float4 a = *(const float4*)(src);
            float4 c = *(const float4*)(src + 4);
            Kt[(size_t)tile * 512 + p] = make_uint4(pack2bf(a.x, a.y), pack2bf(a.z, a.w),
                                                    pack2bf(c.x, c.y), pack2bf(c.z, c.w));
        }
    } else {
        #pragma unroll
        for (int u = 0; u < 2; ++u) {
            int p = u * 256 + tid;
            int q = p & 31, h = (p >> 5) & 1, p64 = p >> 6;
            int d = (p64 >> 1) * 32 + q;
            int k0 = (p64 & 1) * 16 + h * 8;
            unsigned int r[4];
            #pragma unroll
            for (int jj = 0; jj < 4; ++jj)
                r[jj] = pack2bf(TL[(k0 + 2 * jj) * 136 + d],
                                TL[(k0 + 2 * jj + 1) * 136 + d]);
            Vt[(size_t)tile * 512 + p] = make_uint4(r[0], r[1], r[2], r[3]);
        }
    }
}

// ---- main attention + fused split-k reduce --------------------------------
// Grid 512 = 64 qt(128 q) x 8 ks(1024 keys); block 256 = 4 waves = 4 q-groups
// of 32 q. Each wave streams all 32 key-tiles of its ks slice. K tiles via
// LDS double-buffer (shared by the 4 waves, 1 barrier/iter); V fragments
// streamed straight from L2 (identical addresses across waves -> L1 reuse).
// Q converted fp32->bf16 in-kernel. Last-arriving WG per qt reduces.
// No softmax max-shift (|scores| < ~1 at 1/sqrt(8192) scale).
__global__ __launch_bounds__(256) void attn_kernel(
        const float* __restrict__ Q,
        const uint4* __restrict__ Kt, const uint4* __restrict__ Vt,
        unsigned short* __restrict__ Opart, float* __restrict__ Lpart,
        int* __restrict__ cnt, float* __restrict__ Out) {
    __shared__ __align__(16) char smem[17408];   // kbuf 16K | reducer T/Linv
    __shared__ int redflag;
    const int tid = threadIdx.x;
    const int qg = tid >> 6, lane = tid & 63;
    const int q = lane & 31, h = lane >> 5;
    const int ks = blockIdx.x & 7, qt = blockIdx.x >> 3;
    const int qbase = qt * 128 + qg * 32;
    const int tile0 = ks * 32;

    // Q fragments: direct fp32 loads, scale by CL2, pack (one-time)
    uint4 qf[8];
    {
        const float4* Qr = (const float4*)Q + (size_t)(qbase + q) * 32 + 2 * h;
        #pragma unroll
        for (int s = 0; s < 8; ++s) {
            float4 a = Qr[4 * s], b = Qr[4 * s + 1];
            qf[s] = make_uint4(pack2bf(a.x * CL2, a.y * CL2),
                               pack2bf(a.z * CL2, a.w * CL2),
                               pack2bf(b.x * CL2, b.y * CL2),
                               pack2bf(b.z * CL2, b.w * CL2));
        }
    }

    f32x16 oacc[4];
    #pragma unroll
    for (int a = 0; a < 4; ++a)
        #pragma unroll
        for (int r = 0; r < 16; ++r) oacc[a][r] = 0.f;
    float lsum = 0.f;

    // stage K tile t into LDS buffer (4 waves cooperate: 2 chunks each)
    auto stage = [&](int buf, int t) {
        const uint4* src = Kt + (size_t)(tile0 + t) * 512 + qg * 128 + lane;
        gl_lds16(src,      smem + buf * 8192 + (qg * 2) * 1024);
        gl_lds16(src + 64, smem + buf * 8192 + (qg * 2 + 1) * 1024);
    };

    stage(0, 0);
    __syncthreads();
    #pragma unroll 1
    for (int t = 0; t < 32; ++t) {
        if (t < 31) stage((t + 1) & 1, t + 1);
        const char* kl = smem + (t & 1) * 8192 + lane * 16;

        uint4 kf[8];
        #pragma unroll
        for (int s = 0; s < 8; ++s) kf[s] = *(const uint4*)(kl + s * 1024);

        f32x16 sacc;
        #pragma unroll
        for (int r = 0; r < 16; ++r) sacc[r] = 0.f;
        #pragma unroll
        for (int s = 0; s < 8; ++s)
            sacc = __builtin_amdgcn_mfma_f32_32x32x16_bf16(
                       as_frag(kf[s]), as_frag(qf[s]), sacc, 0, 0, 0);

        // V fragments streamed from L2 (coalesced; shared across waves via L1)
        uint4 vf[8];
        const uint4* vsrc = Vt + (size_t)(tile0 + t) * 512 + lane;
        #pragma unroll
        for (int w = 0; w < 8; ++w) vf[w] = vsrc[w * 64];

        float p[16];
        #pragma unroll
        for (int r = 0; r < 16; ++r) {
            p[r] = __builtin_amdgcn_exp2f(sacc[r]);
            lsum += p[r];
        }
        unsigned int pk[8], px[8];
        #pragma unroll
        for (int jj = 0; jj < 8; ++jj) pk[jj] = pack2bf_trunc(p[2 * jj], p[2 * jj + 1]);
        #pragma unroll
        for (int jj = 0; jj < 8; ++jj) px[jj] = (unsigned int)__shfl_xor((int)pk[jj], 32);
        uint4 B0, B1;
        B0.x = h ? px[2] : pk[0];  B0.y = h ? px[3] : pk[1];
        B0.z = h ? pk[2] : px[0];  B0.w = h ? pk[3] : px[1];
        B1.x = h ? px[6] : pk[4];  B1.y = h ? px[7] : pk[5];
        B1.z = h ? pk[6] : px[4];  B1.w = h ? pk[7] : px[5];

        #pragma unroll
        for (int mb = 0; mb < 4; ++mb) {
            oacc[mb] = __builtin_amdgcn_mfma_f32_32x32x16_bf16(
                           as_frag(vf[2 * mb]), as_frag(B0), oacc[mb], 0, 0, 0);
            oacc[mb] = __builtin_amdgcn_mfma_f32_32x32x16_bf16(
                           as_frag(vf[2 * mb + 1]), as_frag(B1), oacc[mb], 0, 0, 0);
        }
        __syncthreads();    // dbuf rotate (drains staging, protects reads)
    }

    // ---- store bf16 partial in raw C-layout + L, then split-k handshake ---
    float l2 = lsum + __shfl_xor(lsum, 32);
    if (h == 0) Lpart[ks * SEQ + qbase + q] = l2;
    {
        unsigned short* dst = Opart + ((size_t)(ks * 256 + qt * 4 + qg)) * 4096
                              + lane * 16;
        #pragma unroll
        for (int a = 0; a < 4; ++a) {
            unsigned int o[8];
            #pragma unroll
            for (int u = 0; u < 8; ++u)
                o[u] = pack2bf(oacc[a][2 * u], oacc[a][2 * u + 1]);
            *(uint4*)(dst + a * 1024)     = make_uint4(o[0], o[1], o[2], o[3]);
            *(uint4*)(dst + a * 1024 + 8) = make_uint4(o[4], o[5], o[6], o[7]);
        }
    }
    __threadfence();                 // release: partials visible device-wide
    __syncthreads();
    if (tid == 0) redflag = (atomicAdd(&cnt[qt], 1) == NKS - 1);
    __syncthreads();
    if (!redflag) return;
    __threadfence();                 // acquire: see other XCDs' partials

    // ---- fused reduction for this qt: 4 tiles of 32 q ---------------------
    float* T    = (float*)smem;              // [128 d][33 pad]
    float* Linv = (float*)(smem + 16896);    // [32]
    const int A = tid >> 6, l = tid & 63, hh = l >> 5, qq = l & 31;
    #pragma unroll 1
    for (int tq = 0; tq < 4; ++tq) {
        const int tile_id = qt * 4 + tq;
        float acc[16];
        #pragma unroll
        for (int r = 0; r < 16; ++r) acc[r] = 0.f;
        #pragma unroll 1
        for (int k2 = 0; k2 < NKS; ++k2) {
            const uint4* s4 = (const uint4*)(Opart
                + ((size_t)(k2 * 256 + tile_id)) * 4096 + A * 1024 + l * 16);
            uint4 v0 = s4[0], v1 = s4[1];
            acc[0] += bflo(v0.x);  acc[1] += bfhi(v0.x);
            acc[2] += bflo(v0.y);  acc[3] += bfhi(v0.y);
            acc[4] += bflo(v0.z);  acc[5] += bfhi(v0.z);
            acc[6] += bflo(v0.w);  acc[7] += bfhi(v0.w);
            acc[8] += bflo(v1.x);  acc[9] += bfhi(v1.x);
            acc[10] += bflo(v1.y); acc[11] += bfhi(v1.y);
            acc[12] += bflo(v1.z); acc[13] += bfhi(v1.z);
            acc[14] += bflo(v1.w); acc[15] += bfhi(v1.w);
        }
        if (tid < 32) {
            float L = 0.f;
            #pragma unroll
            for (int k2 = 0; k2 < NKS; ++k2)
                L += Lpart[k2 * SEQ + qt * 128 + tq * 32 + tid];
            Linv[tid] = 1.0f / L;
        }
        #pragma unroll
        for (int r = 0; r < 16; ++r) {
            int d = A * 32 + (r & 3) + 8 * (r >> 2) + 4 * hh;
            T[d * 33 + qq] = acc[r];
        }
        __syncthreads();
        const int row = tid >> 3, seg = (tid & 7) * 16;
        const float rv = Linv[row];
        #pragma unroll
        for (int e = 0; e < 16; e += 4) {
            float4 o = make_float4(T[(seg + e + 0) * 33 + row] * rv,
                                   T[(seg + e + 1) * 33 + row] * rv,
                                   T[(seg + e + 2) * 33 + row] * rv,
                                   T[(seg + e + 3) * 33 + row] * rv);
            *(float4*)(Out + (size_t)(tile_id * 32 + row) * DM + seg + e) = o;
        }
        __syncthreads();
    }
}

extern "C" void kernel_launch(void* const* d_in, const int* in_sizes, int n_in,
                              void* d_out, int out_size, void* d_ws, size_t ws_size,
                              hipStream_t stream) {
    const float* Q = (const float*)d_in[0];
    const float* K = (const float*)d_in[1];
    const float* V = (const float*)d_in[2];
    char* ws = (char*)d_ws;
    uint4* Kt            = (uint4*)ws;                                   // 2 MiB
    uint4* Vt            = (uint4*)(ws + 2 * 1024 * 1024);               // 2 MiB
    float* Lpart         = (float*)(ws + 4 * 1024 * 1024);               // 256 KiB
    int*   cnt           = (int*)(ws + 4 * 1024 * 1024 + 262144);        // 256 B
    unsigned short* Opart= (unsigned short*)(ws + 4 * 1024 * 1024 + 262144 + 1024); // 16 MiB
    float* Out = (float*)d_out;                     // ws use: ~20.26 MiB

    prep_kernel<<<512, 256, 0, stream>>>(K, V, Kt, Vt, cnt);
    attn_kernel<<<512, 256, 0, stream>>>(Q, Kt, Vt, Opart, Lpart, cnt, Out);
}

// Round 8
// 196.072 us; speedup vs baseline: 1.0795x; 1.0795x over previous
//
#include <hip/hip_runtime.h>

#define SEQ 8192
#define DM  128
#define NKS 8            // k-splits (1024 keys each)

typedef __attribute__((ext_vector_type(8)))  short bf16x8;
typedef __attribute__((ext_vector_type(16))) float f32x16;

static __device__ __forceinline__ unsigned short f2bf(float f) {
    unsigned int u = __builtin_bit_cast(unsigned int, f);
    u += 0x7FFFu + ((u >> 16) & 1u);
    return (unsigned short)(u >> 16);
}
static __device__ __forceinline__ unsigned int pack2bf(float a, float b) {
    return ((unsigned int)f2bf(b) << 16) | (unsigned int)f2bf(a);
}
static __device__ __forceinline__ float bflo(unsigned int u) {
    return __builtin_bit_cast(float, u << 16);
}
static __device__ __forceinline__ float bfhi(unsigned int u) {
    return __builtin_bit_cast(float, u & 0xFFFF0000u);
}
static __device__ __forceinline__ bf16x8 as_frag(uint4 v) {
    return __builtin_bit_cast(bf16x8, v);
}
static __device__ __forceinline__ unsigned int pack2bf_trunc(float a, float b) {
    return __builtin_amdgcn_perm(__builtin_bit_cast(unsigned int, b),
                                 __builtin_bit_cast(unsigned int, a), 0x07060302u);
}
static __device__ __forceinline__ void gl_lds16(const void* g, void* l) {
    __builtin_amdgcn_global_load_lds(
        (const __attribute__((address_space(1))) void*)(unsigned long long)g,
        (__attribute__((address_space(3))) void*)(unsigned int)(unsigned long long)l,
        16, 0, 0);
}
#define CL2 (1.4426950408889634f / 90.50966799187809f)   // log2(e)/sqrt(8192)

// ---- prep: 768 blocks; b<256: Q (scaled), <512: K, <768: V ---------------
// Fragment-order tiles (chunk p = s*64 + h*32 + q, 16B chunks):
//   Qt/Kt: chunk(p) = X[tile*32+q][16s+8h .. +8)
//   Vt:    chunk(p) = V^T[32*(p64>>1)+q][tile*32 + 16*(p64&1)+8h .. +8)
__global__ __launch_bounds__(256) void prep_kernel(
        const float* __restrict__ Q, const float* __restrict__ K,
        const float* __restrict__ V,
        uint4* __restrict__ Qt, uint4* __restrict__ Kt, uint4* __restrict__ Vt,
        int* __restrict__ cnt) {
    __shared__ float TL[32 * 136];
    const int b = blockIdx.x, tid = threadIdx.x;
    const int which = b >> 8, tile = b & 255;
    if (b == 0 && tid < 64) cnt[tid] = 0;
    const float4* S4 = (which == 0) ? (const float4*)Q
                     : (which == 1) ? (const float4*)K : (const float4*)V;
    #pragma unroll
    for (int u = 0; u < 4; ++u) {
        int f4 = u * 256 + tid;
        int k = f4 >> 5, c4 = f4 & 31;
        float4 v = S4[(size_t)tile * 1024 + f4];
        *(float4*)(TL + k * 136 + c4 * 4) = v;
    }
    __syncthreads();
    if (which < 2) {
        const float scale = (which == 0) ? (float)CL2 : 1.0f;
        uint4* dst = ((which == 0) ? Qt : Kt) + (size_t)tile * 512;
        #pragma unroll
        for (int u = 0; u < 2; ++u) {
            int p = u * 256 + tid;
            int q = p & 31, h = (p >> 5) & 1, s = p >> 6;
            const float* src = TL + q * 136 + s * 16 + h * 8;
            float4 a = *(const float4*)(src);
            float4 c = *(const float4*)(src + 4);
            dst[p] = make_uint4(pack2bf(a.x * scale, a.y * scale),
                                pack2bf(a.z * scale, a.w * scale),
                                pack2bf(c.x * scale, c.y * scale),
                                pack2bf(c.z * scale, c.w * scale));
        }
    } else {
        uint4* dst = Vt + (size_t)tile * 512;
        #pragma unroll
        for (int u = 0; u < 2; ++u) {
            int p = u * 256 + tid;
            int q = p & 31, h = (p >> 5) & 1, p64 = p >> 6;
            int d = (p64 >> 1) * 32 + q;
            int k0 = (p64 & 1) * 16 + h * 8;
            unsigned int r[4];
            #pragma unroll
            for (int jj = 0; jj < 4; ++jj)
                r[jj] = pack2bf(TL[(k0 + 2 * jj) * 136 + d],
                                TL[(k0 + 2 * jj + 1) * 136 + d]);
            dst[p] = make_uint4(r[0], r[1], r[2], r[3]);
        }
    }
}

// ---- main attention + fused split-k reduce --------------------------------
// Grid 256 = 32 qt(256 q) x 8 ks(1024 keys); 1 WG/CU. Block 512 = 8 waves =
// 4 q-groups(64 q) x 2 k-subslices(512 keys = 16 tiles). Q (64 KB) + KV
// double-buffer (2x2x16 KB) in LDS. One barrier per tile. g0/g1 processed
// sequentially so only one S-accumulator is ever live (reg budget 256).
// In-WG subslice combine; last WG per qt reduces the 8 splits and writes Out.
// No softmax max-shift (|scores| < ~1 at 1/sqrt(8192) scale).
__global__ __launch_bounds__(512, 2) void attn_kernel(
        const uint4* __restrict__ Qt, const uint4* __restrict__ Kt,
        const uint4* __restrict__ Vt,
        unsigned short* __restrict__ Opart, float* __restrict__ Lpart,
        int* __restrict__ cnt, float* __restrict__ Out) {
    __shared__ __align__(16) char smem[133120];  // [0,64K) Q | [64K,128K) KV | Lw
    __shared__ int redflag;
    const int tid = threadIdx.x;
    const int wid = tid >> 6, lane = tid & 63;
    const int qg = wid & 3, sub = wid >> 2;
    const int q = lane & 31, h = lane >> 5;
    const int ks = blockIdx.x & 7, qt = blockIdx.x >> 3;

    char* const qlds = smem + qg * 16384;        // this q-group's 64-q Q frags
    // stage Q once: 16 chunks of 1 KB per q-group; each sub-wave stages 8
    {
        const uint4* qsrc = Qt + ((size_t)(qt * 8 + qg * 2)) * 512;
        #pragma unroll
        for (int i = 0; i < 8; ++i) {
            int c = sub * 8 + i;
            gl_lds16(qsrc + c * 64 + lane, qlds + c * 1024);
        }
    }

    f32x16 oacc[8];          // [g][mb] -> g*4+mb
    #pragma unroll
    for (int a = 0; a < 8; ++a)
        #pragma unroll
        for (int r = 0; r < 16; ++r) oacc[a][r] = 0.f;
    float ls0 = 0.f, ls1 = 0.f;

    // KV staging: per sub, 16 KB tile (K 8K | V 8K); 4 qg-waves do 4 chunks ea.
    const int tile0 = ks * 32 + sub * 16;
    auto stage = [&](int buf, int t) {
        const uint4* ksrc = Kt + (size_t)(tile0 + t) * 512 + (qg * 2) * 64 + lane;
        const uint4* vsrc = Vt + (size_t)(tile0 + t) * 512 + (qg * 2) * 64 + lane;
        char* base = smem + 65536 + sub * 32768 + buf * 16384;
        gl_lds16(ksrc,      base + qg * 2048);
        gl_lds16(ksrc + 64, base + qg * 2048 + 1024);
        gl_lds16(vsrc,      base + 8192 + qg * 2048);
        gl_lds16(vsrc + 64, base + 8192 + qg * 2048 + 1024);
    };

    stage(0, 0);
    __syncthreads();
    #pragma unroll 1
    for (int t = 0; t < 16; ++t) {
        if (t < 15) stage((t + 1) & 1, t + 1);
        const char* kb = smem + 65536 + sub * 32768 + (t & 1) * 16384 + lane * 16;

        uint4 kf[8];
        #pragma unroll
        for (int s = 0; s < 8; ++s) kf[s] = *(const uint4*)(kb + s * 1024);

        #pragma unroll
        for (int g = 0; g < 2; ++g) {
            f32x16 sacc;
            #pragma unroll
            for (int r = 0; r < 16; ++r) sacc[r] = 0.f;
            #pragma unroll
            for (int s = 0; s < 8; ++s) {
                bf16x8 qa = *(const bf16x8*)(qlds + g * 8192 + s * 1024 + lane * 16);
                sacc = __builtin_amdgcn_mfma_f32_32x32x16_bf16(
                           as_frag(kf[s]), qa, sacc, 0, 0, 0);
            }
            float p[16];
            #pragma unroll
            for (int r = 0; r < 16; ++r) {
                p[r] = __builtin_amdgcn_exp2f(sacc[r]);
                if (g) ls1 += p[r]; else ls0 += p[r];
            }
            unsigned int pk[8], px[8];
            #pragma unroll
            for (int jj = 0; jj < 8; ++jj) pk[jj] = pack2bf_trunc(p[2 * jj], p[2 * jj + 1]);
            #pragma unroll
            for (int jj = 0; jj < 8; ++jj) px[jj] = (unsigned int)__shfl_xor((int)pk[jj], 32);
            uint4 B0, B1;
            B0.x = h ? px[2] : pk[0];  B0.y = h ? px[3] : pk[1];
            B0.z = h ? pk[2] : px[0];  B0.w = h ? pk[3] : px[1];
            B1.x = h ? px[6] : pk[4];  B1.y = h ? px[7] : pk[5];
            B1.z = h ? pk[6] : px[4];  B1.w = h ? pk[7] : px[5];
            #pragma unroll
            for (int mb = 0; mb < 4; ++mb) {
                uint4 va = *(const uint4*)(kb + 8192 + (2 * mb) * 1024);
                uint4 vb = *(const uint4*)(kb + 8192 + (2 * mb + 1) * 1024);
                oacc[g * 4 + mb] = __builtin_amdgcn_mfma_f32_32x32x16_bf16(
                    as_frag(va), as_frag(B0), oacc[g * 4 + mb], 0, 0, 0);
                oacc[g * 4 + mb] = __builtin_amdgcn_mfma_f32_32x32x16_bf16(
                    as_frag(vb), as_frag(B1), oacc[g * 4 + mb], 0, 0, 0);
            }
        }
        __syncthreads();   // dbuf rotate (drains staging, protects reads)
    }

    // ---- in-WG combine of the 2 k-subslices -------------------------------
    float l20 = ls0 + __shfl_xor(ls0, 32);
    float l21 = ls1 + __shfl_xor(ls1, 32);
    float* Lw = (float*)(smem + 131072);          // [8 waves][64]
    if (h == 0) { Lw[wid * 64 + q] = l20; Lw[wid * 64 + 32 + q] = l21; }
    __syncthreads();
    if (sub == 1) {        // dump raw accs into the (dead) Q+KV arena
        float* D = (float*)(smem + qg * 32768);
        #pragma unroll
        for (int a = 0; a < 8; ++a)
            #pragma unroll
            for (int r = 0; r < 16; ++r)
                D[(a * 16 + r) * 64 + lane] = oacc[a][r];
    }
    __syncthreads();
    if (sub == 0) {
        const float* D = (const float*)(smem + qg * 32768);
        #pragma unroll
        for (int a = 0; a < 8; ++a)
            #pragma unroll
            for (int r = 0; r < 16; ++r)
                oacc[a][r] += D[(a * 16 + r) * 64 + lane];
        #pragma unroll
        for (int g = 0; g < 2; ++g) {
            int tile_id = qt * 8 + qg * 2 + g;
            if (h == 0) {
                float lother = Lw[(4 + qg) * 64 + g * 32 + q];
                Lpart[ks * SEQ + tile_id * 32 + q] = (g ? l21 : l20) + lother;
            }
            unsigned short* dst = Opart + ((size_t)(ks * 256 + tile_id)) * 4096
                                  + lane * 16;
            #pragma unroll
            for (int a = 0; a < 4; ++a) {
                unsigned int o[8];
                #pragma unroll
                for (int u = 0; u < 8; ++u)
                    o[u] = pack2bf(oacc[g * 4 + a][2 * u], oacc[g * 4 + a][2 * u + 1]);
                *(uint4*)(dst + a * 1024)     = make_uint4(o[0], o[1], o[2], o[3]);
                *(uint4*)(dst + a * 1024 + 8) = make_uint4(o[4], o[5], o[6], o[7]);
            }
        }
    }
    __threadfence();                 // release: partials visible device-wide
    __syncthreads();
    if (tid == 0) redflag = (atomicAdd(&cnt[qt], 1) == NKS - 1);
    __syncthreads();
    if (!redflag) return;
    __threadfence();                 // acquire: see other XCDs' partials

    // ---- fused reduction for this qt: 8 tiles of 32 q, 2 groups x 4 -------
    const int grp = tid >> 8, lt = tid & 255;
    float* T    = (float*)(smem + grp * 17408);        // [128 d][33 pad]
    float* Linv = (float*)(smem + grp * 17408 + 16896); // [32]
    const int A = lt >> 6, l = lt & 63, hh = l >> 5, qq = l & 31;
    #pragma unroll 1
    for (int tq = 0; tq < 4; ++tq) {
        const int tile_id = qt * 8 + grp * 4 + tq;
        float acc[16];
        #pragma unroll
        for (int r = 0; r < 16; ++r) acc[r] = 0.f;
        #pragma unroll 1
        for (int k2 = 0; k2 < NKS; ++k2) {
            const uint4* s4 = (const uint4*)(Opart
                + ((size_t)(k2 * 256 + tile_id)) * 4096 + A * 1024 + l * 16);
            uint4 v0 = s4[0], v1 = s4[1];
            acc[0] += bflo(v0.x);  acc[1] += bfhi(v0.x);
            acc[2] += bflo(v0.y);  acc[3] += bfhi(v0.y);
            acc[4] += bflo(v0.z);  acc[5] += bfhi(v0.z);
            acc[6] += bflo(v0.w);  acc[7] += bfhi(v0.w);
            acc[8] += bflo(v1.x);  acc[9] += bfhi(v1.x);
            acc[10] += bflo(v1.y); acc[11] += bfhi(v1.y);
            acc[12] += bflo(v1.z); acc[13] += bfhi(v1.z);
            acc[14] += bflo(v1.w); acc[15] += bfhi(v1.w);
        }
        if (lt < 32) {
            float L = 0.f;
            #pragma unroll
            for (int k2 = 0; k2 < NKS; ++k2)
                L += Lpart[k2 * SEQ + tile_id * 32 + lt];
            Linv[lt] = 1.0f / L;
        }
        #pragma unroll
        for (int r = 0; r < 16; ++r) {
            int d = A * 32 + (r & 3) + 8 * (r >> 2) + 4 * hh;
            T[d * 33 + qq] = acc[r];
        }
        __syncthreads();
        const int row = lt >> 3, seg = (lt & 7) * 16;
        const float rv = Linv[row];
        #pragma unroll
        for (int e = 0; e < 16; e += 4) {
            float4 o = make_float4(T[(seg + e + 0) * 33 + row] * rv,
                                   T[(seg + e + 1) * 33 + row] * rv,
                                   T[(seg + e + 2) * 33 + row] * rv,
                                   T[(seg + e + 3) * 33 + row] * rv);
            *(float4*)(Out + (size_t)(tile_id * 32 + row) * DM + seg + e) = o;
        }
        __syncthreads();
    }
}

extern "C" void kernel_launch(void* const* d_in, const int* in_sizes, int n_in,
                              void* d_out, int out_size, void* d_ws, size_t ws_size,
                              hipStream_t stream) {
    const float* Q = (const float*)d_in[0];
    const float* K = (const float*)d_in[1];
    const float* V = (const float*)d_in[2];
    char* ws = (char*)d_ws;
    uint4* Qt            = (uint4*)ws;                                   // 2 MiB
    uint4* Kt            = (uint4*)(ws + 2 * 1024 * 1024);               // 2 MiB
    uint4* Vt            = (uint4*)(ws + 4 * 1024 * 1024);               // 2 MiB
    float* Lpart         = (float*)(ws + 6 * 1024 * 1024);               // 256 KiB
    int*   cnt           = (int*)(ws + 6 * 1024 * 1024 + 262144);        // 256 B
    unsigned short* Opart= (unsigned short*)(ws + 6 * 1024 * 1024 + 262144 + 1024); // 16 MiB
    float* Out = (float*)d_out;                     // ws use: 22.25 MiB (R6-proven)

    prep_kernel<<<768, 256, 0, stream>>>(Q, K, V, Qt, Kt, Vt, cnt);
    attn_kernel<<<256, 512, 0, stream>>>(Qt, Kt, Vt, Opart, Lpart, cnt, Out);
}